// Round 4
// baseline (586.110 us; speedup 1.0000x reference)
//
#include <hip/hip_runtime.h>

#define BATCH 32
#define CIN   256
#define CHALF 128
#define NPIX  3136   // 56*56
#define MPOOL 784    // 28*28
#define MPAD  896    // 784 padded to multiple of 32 (PV K-dim)

typedef __bf16 bf16;
typedef __bf16 bf16x2 __attribute__((ext_vector_type(2)));
typedef __bf16 bf16x4 __attribute__((ext_vector_type(4)));
typedef __bf16 bf16x8 __attribute__((ext_vector_type(8)));
typedef float  f32x4  __attribute__((ext_vector_type(4)));

// ---------------------------------------------------------------------------
// k_cast: W1,W2,W3 fp32 -> Wcat[512][256] bf16
// ---------------------------------------------------------------------------
__global__ __launch_bounds__(256) void k_cast(
    const float* __restrict__ W1, const float* __restrict__ W2,
    const float* __restrict__ W3, bf16* __restrict__ Wcat)
{
    int u = blockIdx.x * 256 + threadIdx.x;
    int o = u >> 6, k4 = (u & 63) * 4;
    const float* src = (o < 128) ? (W1 + o * 256)
                     : (o < 256) ? (W2 + (o - 128) * 256)
                                 : (W3 + (o - 256) * 256);
    float4 v = *(const float4*)(src + k4);
    bf16x4 w = { (bf16)v.x, (bf16)v.y, (bf16)v.z, (bf16)v.w };
    *(bf16x4*)(Wcat + o * 256 + k4) = w;
}

// ---------------------------------------------------------------------------
// k_conv: Y[512 o][112 n] = Wcat * x-slice via MFMA, fused 2x2 max+avg pool.
// grid (28 h2, 32 b), 512 threads. (unchanged from R2)
// ---------------------------------------------------------------------------
#define XS_STRIDE   528
#define SLAB_STRIDE 520

__global__ __launch_bounds__(512) void k_conv(
    const float* __restrict__ x, const bf16* __restrict__ Wcat,
    bf16* __restrict__ c2n, bf16* __restrict__ c1pT, bf16* __restrict__ c3p)
{
    const int h2 = blockIdx.x, b = blockIdx.y;
    const int t = threadIdx.x;
    const int lane = t & 63, wave = t >> 6;
    const int l15 = lane & 15, lg = lane >> 4;

    __shared__ __align__(16) unsigned char smem[59136];

    if (h2 == 0) {
        float4 z = {0.f, 0.f, 0.f, 0.f};
        float4* p1 = (float4*)(c1pT + (size_t)b * MPAD * CHALF + (size_t)MPOOL * CHALF);
        for (int u = t; u < 1792; u += 512) p1[u] = z;
        bf16* p3 = c3p + (size_t)b * CIN * MPAD + MPOOL;
        for (int u = t; u < 256 * 14; u += 512) {
            int c = u / 14, g = u % 14;
            *(float4*)((char*)(p3 + (size_t)c * MPAD) + g * 16) = z;
        }
    }

    {
        const float* xb = x + (size_t)b * CIN * NPIX + h2 * 112;
        float vv[14][4];
        #pragma unroll
        for (int i = 0; i < 14; ++i) {
            int u = t + i * 512;
            int c4 = u / 112, n = u - c4 * 112;
            const float* s = xb + (size_t)(c4 * 4) * NPIX + n;
            vv[i][0] = s[0];
            vv[i][1] = s[NPIX];
            vv[i][2] = s[2 * NPIX];
            vv[i][3] = s[3 * NPIX];
        }
        #pragma unroll
        for (int i = 0; i < 14; ++i) {
            int u = t + i * 512;
            int c4 = u / 112, n = u - c4 * 112;
            bf16x4 w = {(bf16)vv[i][0], (bf16)vv[i][1], (bf16)vv[i][2], (bf16)vv[i][3]};
            *(bf16x4*)(smem + n * XS_STRIDE + c4 * 8) = w;
        }
    }
    __syncthreads();

    f32x4 acc[4][7];
    #pragma unroll
    for (int fo = 0; fo < 4; ++fo)
        #pragma unroll
        for (int fn = 0; fn < 7; ++fn) {
            f32x4 zz = {0.f, 0.f, 0.f, 0.f};
            acc[fo][fn] = zz;
        }
    {
        const int o0 = wave * 64;
        const bf16* wbase = Wcat + (size_t)(o0 + l15) * 256 + lg * 8;
        const unsigned char* xsb = smem + l15 * XS_STRIDE + lg * 16;
        #pragma unroll
        for (int ks = 0; ks < 8; ++ks) {
            bf16x8 afr[4], bfr[7];
            #pragma unroll
            for (int fo = 0; fo < 4; ++fo)
                afr[fo] = *(const bf16x8*)(wbase + fo * 16 * 256 + ks * 32);
            #pragma unroll
            for (int fn = 0; fn < 7; ++fn)
                bfr[fn] = *(const bf16x8*)(xsb + fn * 16 * XS_STRIDE + ks * 64);
            #pragma unroll
            for (int fo = 0; fo < 4; ++fo)
                #pragma unroll
                for (int fn = 0; fn < 7; ++fn)
                    acc[fo][fn] = __builtin_amdgcn_mfma_f32_16x16x32_bf16(
                        afr[fo], bfr[fn], acc[fo][fn], 0, 0, 0);
        }
    }

    __syncthreads();
    if (wave < 4) {
        #pragma unroll
        for (int fo = 0; fo < 4; ++fo)
            #pragma unroll
            for (int fn = 0; fn < 7; ++fn) {
                int n = fn * 16 + l15;
                int ol = wave * 64 + fo * 16 + lg * 4;
                f32x4 a = acc[fo][fn];
                bf16x4 w = {(bf16)a[0], (bf16)a[1], (bf16)a[2], (bf16)a[3]};
                *(bf16x4*)(smem + n * SLAB_STRIDE + ol * 2) = w;
            }
    }
    __syncthreads();
    {
        bf16* dst = c1pT + (size_t)b * MPAD * CHALF + (size_t)h2 * 28 * CHALF;
        for (int u = t; u < 896; u += 512) {
            int w2 = u >> 5, o4 = (u & 31) * 4;
            bf16x4 r0 = *(bf16x4*)(smem + (2 * w2)      * SLAB_STRIDE + o4 * 2);
            bf16x4 r1 = *(bf16x4*)(smem + (2 * w2 + 1)  * SLAB_STRIDE + o4 * 2);
            bf16x4 r2 = *(bf16x4*)(smem + (56 + 2 * w2) * SLAB_STRIDE + o4 * 2);
            bf16x4 r3 = *(bf16x4*)(smem + (57 + 2 * w2) * SLAB_STRIDE + o4 * 2);
            bf16x4 o_;
            #pragma unroll
            for (int j = 0; j < 4; ++j) {
                float p0 = (float)r0[j], p1 = (float)r1[j];
                float p2 = (float)r2[j], p3 = (float)r3[j];
                float mx = fmaxf(fmaxf(p0, p1), fmaxf(p2, p3));
                float av = (p0 + p1 + p2 + p3) * 0.25f;
                o_[j] = (bf16)(mx + av);
            }
            *(bf16x4*)(dst + (size_t)w2 * CHALF + o4) = o_;
        }
    }
    {
        bf16* dst = c2n + (size_t)b * NPIX * CHALF + (size_t)h2 * 112 * CHALF;
        for (int u = t; u < 3584; u += 512) {
            int n = u >> 5, o4 = (u & 31) * 4;
            bf16x4 v = *(bf16x4*)(smem + n * SLAB_STRIDE + 256 + o4 * 2);
            *(bf16x4*)(dst + (size_t)n * CHALF + o4) = v;
        }
    }

    __syncthreads();
    if (wave >= 4) {
        #pragma unroll
        for (int fo = 0; fo < 4; ++fo)
            #pragma unroll
            for (int fn = 0; fn < 7; ++fn) {
                int n = fn * 16 + l15;
                int ol = (wave - 4) * 64 + fo * 16 + lg * 4;
                f32x4 a = acc[fo][fn];
                bf16x4 w = {(bf16)a[0], (bf16)a[1], (bf16)a[2], (bf16)a[3]};
                *(bf16x4*)(smem + n * SLAB_STRIDE + ol * 2) = w;
            }
    }
    __syncthreads();
    {
        bf16* dst = c3p + (size_t)b * CIN * MPAD + h2 * 28;
        for (int u = t; u < 3584; u += 512) {
            int c = u / 14, w2p = u - c * 14;
            bf16x2 o_;
            #pragma unroll
            for (int k = 0; k < 2; ++k) {
                int w2 = 2 * w2p + k;
                float p0 = (float)*(bf16*)(smem + (2 * w2)      * SLAB_STRIDE + c * 2);
                float p1 = (float)*(bf16*)(smem + (2 * w2 + 1)  * SLAB_STRIDE + c * 2);
                float p2 = (float)*(bf16*)(smem + (56 + 2 * w2) * SLAB_STRIDE + c * 2);
                float p3 = (float)*(bf16*)(smem + (57 + 2 * w2) * SLAB_STRIDE + c * 2);
                float mx = fmaxf(fmaxf(p0, p1), fmaxf(p2, p3));
                float av = (p0 + p1 + p2 + p3) * 0.25f;
                o_[k] = (bf16)(mx + av);
            }
            *(bf16x2*)(dst + (size_t)c * MPAD + 2 * w2p) = o_;
        }
    }
}

// ---------------------------------------------------------------------------
// k_attn: 32-row n-tile, 8 waves (wn = n-half of 16 rows, wq = m/c quarter).
// LDS 56 KB (S tile [32][896] bf16, XOR-swizzled) -> 2 blocks/CU, 4 waves/SIMD.
// Fully-unrolled MFMA loops so the scheduler hoists global loads deep.
// 1D grid 3136 with XCD swizzle: all 98 n-tiles of batch b on one XCD.
// ---------------------------------------------------------------------------
__global__ __launch_bounds__(512, 4) void k_attn(
    const bf16* __restrict__ c2n,
    const bf16* __restrict__ c1pT,
    const bf16* __restrict__ c3p,
    const float* __restrict__ x,
    const float* __restrict__ gamma,
    float* __restrict__ out)
{
    const int bid = blockIdx.x;             // 3136 = 8 xcd * 4 b * 98 nb
    const int slot = bid >> 3;              // 0..391
    const int b  = (bid & 7) + 8 * (slot / 98);
    const int nb = slot % 98;
    const int n0 = nb * 32;
    const int t = threadIdx.x;
    const int lane = t & 63, wave = t >> 6;
    const int l15 = lane & 15, lg = lane >> 4;
    const int wn = wave >> 2, wq = wave & 3;

    __shared__ __align__(16) unsigned char smem[57344];   // 32*1792
    float* R = (float*)smem;                               // epilogue [32][257]

    // ---------------- Phase S: S[32n][896m] = c2n(32x128) * c1pT^T ----------
    bf16x8 afr[4];
    {
        const bf16* an = c2n + ((size_t)b * NPIX + n0 + wn * 16 + l15) * CHALF + lg * 8;
        #pragma unroll
        for (int k = 0; k < 4; ++k)
            afr[k] = *(const bf16x8*)(an + k * 32);
    }
    f32x4 acc[14];
    #pragma unroll
    for (int mf = 0; mf < 14; ++mf) {
        f32x4 z = {0.f, 0.f, 0.f, 0.f};
        acc[mf] = z;
    }
    {
        const bf16* c1b = c1pT + ((size_t)b * MPAD + wq * 224 + l15) * CHALF + lg * 8;
        #pragma unroll
        for (int mf = 0; mf < 14; ++mf) {
            bf16x8 bfr[4];
            #pragma unroll
            for (int k = 0; k < 4; ++k)
                bfr[k] = *(const bf16x8*)(c1b + (size_t)mf * 16 * CHALF + k * 32);
            #pragma unroll
            for (int k = 0; k < 4; ++k)
                acc[mf] = __builtin_amdgcn_mfma_f32_16x16x32_bf16(afr[k], bfr[k], acc[mf], 0, 0, 0);
        }
    }
    // write S (bf16, swizzled): col m = l15-part, rows n = lg*4 + r
    #pragma unroll
    for (int mf = 0; mf < 14; ++mf) {
        int m = wq * 224 + mf * 16 + l15;
        #pragma unroll
        for (int r = 0; r < 4; ++r) {
            int n = wn * 16 + lg * 4 + r;
            int byte = (n * 1792 + m * 2) ^ ((n & 7) << 4);
            *(bf16*)(smem + byte) = (bf16)acc[mf][r];
        }
    }
    __syncthreads();

    // ---------------- softmax over m (4 rows per wave) ----------------------
    #pragma unroll
    for (int rr = 0; rr < 4; ++rr) {
        int n = wave * 4 + rr;
        int rowbase = n * 1792, sw = (n & 7) << 4;
        float v[13];
        float mx = -1e30f;
        #pragma unroll
        for (int i = 0; i < 13; ++i) {
            int m = lane + 64 * i;
            v[i] = (m < MPOOL) ? (float)*(const bf16*)(smem + ((rowbase + 2 * m) ^ sw))
                               : -1e30f;
            mx = fmaxf(mx, v[i]);
        }
        #pragma unroll
        for (int off = 32; off; off >>= 1) mx = fmaxf(mx, __shfl_xor(mx, off));
        float s = 0.f;
        float e[13];
        #pragma unroll
        for (int i = 0; i < 13; ++i) {
            int m = lane + 64 * i;
            e[i] = (m < MPOOL) ? __expf(v[i] - mx) : 0.f;
            s += e[i];
        }
        #pragma unroll
        for (int off = 32; off; off >>= 1) s += __shfl_xor(s, off);
        float ri = 1.f / s;
        #pragma unroll
        for (int i = 0; i < 14; ++i) {
            int m = lane + 64 * i;
            float pv = (i < 13) ? e[i] * ri : 0.f;
            *(bf16*)(smem + ((rowbase + 2 * m) ^ sw)) = (bf16)pv;
        }
    }
    __syncthreads();

    // ---------------- Phase PV: refined[n][c] = P(32x896) * c3p^T -----------
    f32x4 acc2[4];
    #pragma unroll
    for (int fc = 0; fc < 4; ++fc) {
        f32x4 z = {0.f, 0.f, 0.f, 0.f};
        acc2[fc] = z;
    }
    {
        const bf16* c3w = c3p + ((size_t)b * CIN + wq * 64 + l15) * MPAD + lg * 8;
        const int nA = wn * 16 + l15;
        const int rowbase = nA * 1792, sw = (nA & 7) << 4;
        #pragma unroll
        for (int ks = 0; ks < 28; ++ks) {
            bf16x8 af = *(const bf16x8*)(smem + ((rowbase + (ks * 32 + lg * 8) * 2) ^ sw));
            #pragma unroll
            for (int fc = 0; fc < 4; ++fc) {
                bf16x8 bfr = *(const bf16x8*)(c3w + (size_t)fc * 16 * MPAD + ks * 32);
                acc2[fc] = __builtin_amdgcn_mfma_f32_16x16x32_bf16(af, bfr, acc2[fc], 0, 0, 0);
            }
        }
    }

    // ---------------- epilogue: transpose via LDS, out = g*refined + x ------
    __syncthreads();
    #pragma unroll
    for (int fc = 0; fc < 4; ++fc) {
        int c = wq * 64 + fc * 16 + l15;
        #pragma unroll
        for (int r = 0; r < 4; ++r) {
            int n = wn * 16 + lg * 4 + r;
            R[n * 257 + c] = acc2[fc][r];
        }
    }
    __syncthreads();
    const float g = gamma[0];
    const float* xb = x + (size_t)b * CIN * NPIX + n0;
    float* ob = out + (size_t)b * CIN * NPIX + n0;
    #pragma unroll 4
    for (int i = 0; i < 16; ++i) {
        int idx = t + i * 512;                  // 256 c x 32 n
        int c = idx >> 5, nn = idx & 31;
        size_t off = (size_t)c * NPIX + nn;
        ob[off] = g * R[nn * 257 + c] + xb[off];
    }
}

extern "C" void kernel_launch(void* const* d_in, const int* in_sizes, int n_in,
                              void* d_out, int out_size, void* d_ws, size_t ws_size,
                              hipStream_t stream) {
    const float* x     = (const float*)d_in[0];
    const float* W1    = (const float*)d_in[1];
    const float* W2    = (const float*)d_in[2];
    const float* W3    = (const float*)d_in[3];
    const float* gamma = (const float*)d_in[4];
    float* out = (float*)d_out;

    bf16* ws   = (bf16*)d_ws;
    bf16* Wcat = ws;                                       // 512*256
    bf16* c2n  = Wcat + (size_t)512 * 256;                 // 32*3136*128
    bf16* c1pT = c2n + (size_t)BATCH * NPIX * CHALF;       // 32*896*128
    bf16* c3p  = c1pT + (size_t)BATCH * MPAD * CHALF;      // 32*256*896

    k_cast<<<128, 256, 0, stream>>>(W1, W2, W3, Wcat);
    k_conv<<<dim3(28, BATCH), 512, 0, stream>>>(x, Wcat, c2n, c1pT, c3p);
    k_attn<<<3136, 512, 0, stream>>>(c2n, c1pT, c3p, x, gamma, out);
}

// Round 5
// 282.784 us; speedup vs baseline: 2.0726x; 2.0726x over previous
//
#include <hip/hip_runtime.h>

#define BATCH 32
#define CIN   256
#define CHALF 128
#define NPIX  3136   // 56*56
#define MPOOL 784    // 28*28
#define MPAD  896    // 784 padded to multiple of 32 (PV K-dim)

typedef __bf16 bf16;
typedef __bf16 bf16x2 __attribute__((ext_vector_type(2)));
typedef __bf16 bf16x4 __attribute__((ext_vector_type(4)));
typedef __bf16 bf16x8 __attribute__((ext_vector_type(8)));
typedef float  f32x4  __attribute__((ext_vector_type(4)));

// ---------------------------------------------------------------------------
// k_cast: W1,W2,W3 fp32 -> Wcat[512][256] bf16
// ---------------------------------------------------------------------------
__global__ __launch_bounds__(256) void k_cast(
    const float* __restrict__ W1, const float* __restrict__ W2,
    const float* __restrict__ W3, bf16* __restrict__ Wcat)
{
    int u = blockIdx.x * 256 + threadIdx.x;
    int o = u >> 6, k4 = (u & 63) * 4;
    const float* src = (o < 128) ? (W1 + o * 256)
                     : (o < 256) ? (W2 + (o - 128) * 256)
                                 : (W3 + (o - 256) * 256);
    float4 v = *(const float4*)(src + k4);
    bf16x4 w = { (bf16)v.x, (bf16)v.y, (bf16)v.z, (bf16)v.w };
    *(bf16x4*)(Wcat + o * 256 + k4) = w;
}

// ---------------------------------------------------------------------------
// k_conv (unchanged from R3): MFMA 1x1 convs + fused 2x2 max+avg pool.
// ---------------------------------------------------------------------------
#define XS_STRIDE   528
#define SLAB_STRIDE 520

__global__ __launch_bounds__(512) void k_conv(
    const float* __restrict__ x, const bf16* __restrict__ Wcat,
    bf16* __restrict__ c2n, bf16* __restrict__ c1pT, bf16* __restrict__ c3p)
{
    const int h2 = blockIdx.x, b = blockIdx.y;
    const int t = threadIdx.x;
    const int lane = t & 63, wave = t >> 6;
    const int l15 = lane & 15, lg = lane >> 4;

    __shared__ __align__(16) unsigned char smem[59136];

    if (h2 == 0) {
        float4 z = {0.f, 0.f, 0.f, 0.f};
        float4* p1 = (float4*)(c1pT + (size_t)b * MPAD * CHALF + (size_t)MPOOL * CHALF);
        for (int u = t; u < 1792; u += 512) p1[u] = z;
        bf16* p3 = c3p + (size_t)b * CIN * MPAD + MPOOL;
        for (int u = t; u < 256 * 14; u += 512) {
            int c = u / 14, g = u % 14;
            *(float4*)((char*)(p3 + (size_t)c * MPAD) + g * 16) = z;
        }
    }

    {
        const float* xb = x + (size_t)b * CIN * NPIX + h2 * 112;
        float vv[14][4];
        #pragma unroll
        for (int i = 0; i < 14; ++i) {
            int u = t + i * 512;
            int c4 = u / 112, n = u - c4 * 112;
            const float* s = xb + (size_t)(c4 * 4) * NPIX + n;
            vv[i][0] = s[0];
            vv[i][1] = s[NPIX];
            vv[i][2] = s[2 * NPIX];
            vv[i][3] = s[3 * NPIX];
        }
        #pragma unroll
        for (int i = 0; i < 14; ++i) {
            int u = t + i * 512;
            int c4 = u / 112, n = u - c4 * 112;
            bf16x4 w = {(bf16)vv[i][0], (bf16)vv[i][1], (bf16)vv[i][2], (bf16)vv[i][3]};
            *(bf16x4*)(smem + n * XS_STRIDE + c4 * 8) = w;
        }
    }
    __syncthreads();

    f32x4 acc[4][7];
    #pragma unroll
    for (int fo = 0; fo < 4; ++fo)
        #pragma unroll
        for (int fn = 0; fn < 7; ++fn) {
            f32x4 zz = {0.f, 0.f, 0.f, 0.f};
            acc[fo][fn] = zz;
        }
    {
        const int o0 = wave * 64;
        const bf16* wbase = Wcat + (size_t)(o0 + l15) * 256 + lg * 8;
        const unsigned char* xsb = smem + l15 * XS_STRIDE + lg * 16;
        #pragma unroll
        for (int ks = 0; ks < 8; ++ks) {
            bf16x8 afr[4], bfr[7];
            #pragma unroll
            for (int fo = 0; fo < 4; ++fo)
                afr[fo] = *(const bf16x8*)(wbase + fo * 16 * 256 + ks * 32);
            #pragma unroll
            for (int fn = 0; fn < 7; ++fn)
                bfr[fn] = *(const bf16x8*)(xsb + fn * 16 * XS_STRIDE + ks * 64);
            #pragma unroll
            for (int fo = 0; fo < 4; ++fo)
                #pragma unroll
                for (int fn = 0; fn < 7; ++fn)
                    acc[fo][fn] = __builtin_amdgcn_mfma_f32_16x16x32_bf16(
                        afr[fo], bfr[fn], acc[fo][fn], 0, 0, 0);
        }
    }

    __syncthreads();
    if (wave < 4) {
        #pragma unroll
        for (int fo = 0; fo < 4; ++fo)
            #pragma unroll
            for (int fn = 0; fn < 7; ++fn) {
                int n = fn * 16 + l15;
                int ol = wave * 64 + fo * 16 + lg * 4;
                f32x4 a = acc[fo][fn];
                bf16x4 w = {(bf16)a[0], (bf16)a[1], (bf16)a[2], (bf16)a[3]};
                *(bf16x4*)(smem + n * SLAB_STRIDE + ol * 2) = w;
            }
    }
    __syncthreads();
    {
        bf16* dst = c1pT + (size_t)b * MPAD * CHALF + (size_t)h2 * 28 * CHALF;
        for (int u = t; u < 896; u += 512) {
            int w2 = u >> 5, o4 = (u & 31) * 4;
            bf16x4 r0 = *(bf16x4*)(smem + (2 * w2)      * SLAB_STRIDE + o4 * 2);
            bf16x4 r1 = *(bf16x4*)(smem + (2 * w2 + 1)  * SLAB_STRIDE + o4 * 2);
            bf16x4 r2 = *(bf16x4*)(smem + (56 + 2 * w2) * SLAB_STRIDE + o4 * 2);
            bf16x4 r3 = *(bf16x4*)(smem + (57 + 2 * w2) * SLAB_STRIDE + o4 * 2);
            bf16x4 o_;
            #pragma unroll
            for (int j = 0; j < 4; ++j) {
                float p0 = (float)r0[j], p1 = (float)r1[j];
                float p2 = (float)r2[j], p3 = (float)r3[j];
                float mx = fmaxf(fmaxf(p0, p1), fmaxf(p2, p3));
                float av = (p0 + p1 + p2 + p3) * 0.25f;
                o_[j] = (bf16)(mx + av);
            }
            *(bf16x4*)(dst + (size_t)w2 * CHALF + o4) = o_;
        }
    }
    {
        bf16* dst = c2n + (size_t)b * NPIX * CHALF + (size_t)h2 * 112 * CHALF;
        for (int u = t; u < 3584; u += 512) {
            int n = u >> 5, o4 = (u & 31) * 4;
            bf16x4 v = *(bf16x4*)(smem + n * SLAB_STRIDE + 256 + o4 * 2);
            *(bf16x4*)(dst + (size_t)n * CHALF + o4) = v;
        }
    }

    __syncthreads();
    if (wave >= 4) {
        #pragma unroll
        for (int fo = 0; fo < 4; ++fo)
            #pragma unroll
            for (int fn = 0; fn < 7; ++fn) {
                int n = fn * 16 + l15;
                int ol = (wave - 4) * 64 + fo * 16 + lg * 4;
                f32x4 a = acc[fo][fn];
                bf16x4 w = {(bf16)a[0], (bf16)a[1], (bf16)a[2], (bf16)a[3]};
                *(bf16x4*)(smem + n * SLAB_STRIDE + ol * 2) = w;
            }
    }
    __syncthreads();
    {
        bf16* dst = c3p + (size_t)b * CIN * MPAD + h2 * 28;
        for (int u = t; u < 3584; u += 512) {
            int c = u / 14, w2p = u - c * 14;
            bf16x2 o_;
            #pragma unroll
            for (int k = 0; k < 2; ++k) {
                int w2 = 2 * w2p + k;
                float p0 = (float)*(bf16*)(smem + (2 * w2)      * SLAB_STRIDE + c * 2);
                float p1 = (float)*(bf16*)(smem + (2 * w2 + 1)  * SLAB_STRIDE + c * 2);
                float p2 = (float)*(bf16*)(smem + (56 + 2 * w2) * SLAB_STRIDE + c * 2);
                float p3 = (float)*(bf16*)(smem + (57 + 2 * w2) * SLAB_STRIDE + c * 2);
                float mx = fmaxf(fmaxf(p0, p1), fmaxf(p2, p3));
                float av = (p0 + p1 + p2 + p3) * 0.25f;
                o_[k] = (bf16)(mx + av);
            }
            *(bf16x2*)(dst + (size_t)c * MPAD + 2 * w2p) = o_;
        }
    }
}

// ---------------------------------------------------------------------------
// k_attn v3: nt=64, 8 waves, cooperative double-buffered LDS staging of both
// B operands. LDS = S[64][1792B swz] (112KB) + 2x16KB stage = 144 KB.
// Stage layouts use involution slot-swizzles so ds_read_b128 is bank-balanced.
// ---------------------------------------------------------------------------
#define S_BYTES     114688            // 64 * 1792
#define STG_OFF     114688
#define STG_SZ      16384

struct Chunk { uint4 a, b; };

__device__ __forceinline__ Chunk load_s_chunk(const bf16* c1b, int mc, int t) {
    Chunk r;
    int u0 = t, u1 = 512 + t;
    int m0 = u0 >> 4, s0 = u0 & 15;
    int m1 = u1 >> 4, s1 = u1 & 15;
    r.a = *(const uint4*)(c1b + (size_t)(mc * 64 + m0) * CHALF + (s0 ^ (m0 & 15)) * 8);
    r.b = *(const uint4*)(c1b + (size_t)(mc * 64 + m1) * CHALF + (s1 ^ (m1 & 15)) * 8);
    return r;
}
__device__ __forceinline__ Chunk load_pv_chunk(const bf16* c3b, int ks, int t) {
    Chunk r;
    int u0 = t, u1 = 512 + t;
    int c0 = u0 >> 2, s0 = u0 & 3;
    int c1 = u1 >> 2, s1 = u1 & 3;
    r.a = *(const uint4*)(c3b + (size_t)c0 * MPAD + ks * 32 + (s0 ^ (c0 & 3)) * 8);
    r.b = *(const uint4*)(c3b + (size_t)c1 * MPAD + ks * 32 + (s1 ^ (c1 & 3)) * 8);
    return r;
}
__device__ __forceinline__ void write_chunk(unsigned char* sb, const Chunk& r, int t) {
    *(uint4*)(sb + t * 16) = r.a;
    *(uint4*)(sb + (512 + t) * 16) = r.b;
}

__global__ __launch_bounds__(512, 2) void k_attn(
    const bf16* __restrict__ c2n,
    const bf16* __restrict__ c1pT,
    const bf16* __restrict__ c3p,
    const float* __restrict__ x,
    const float* __restrict__ gamma,
    float* __restrict__ out)
{
    const int nb = blockIdx.x, b = blockIdx.y;
    const int n0 = nb * 64;
    const int t = threadIdx.x;
    const int lane = t & 63, wave = t >> 6;
    const int l15 = lane & 15, lg = lane >> 4;
    const int wn = wave >> 2, wq = wave & 3;

    __shared__ __align__(16) unsigned char smem[147456];
    unsigned char* stg0 = smem + STG_OFF;
    unsigned char* stg1 = smem + STG_OFF + STG_SZ;

    const bf16* c1b = c1pT + (size_t)b * MPAD * CHALF;
    const bf16* c3b = c3p + (size_t)b * CIN * MPAD;

    // A-frags (c2n) for phase S: issued first so latency hides under staging
    bf16x8 afr[2][4];
    {
        const bf16* an = c2n + ((size_t)b * NPIX + n0 + wn * 32 + l15) * CHALF + lg * 8;
        #pragma unroll
        for (int fn = 0; fn < 2; ++fn)
            #pragma unroll
            for (int k = 0; k < 4; ++k)
                afr[fn][k] = *(const bf16x8*)(an + (size_t)fn * 16 * CHALF + k * 32);
    }

    // ---------------- Phase S: pipelined over 14 chunks of 64 m -------------
    Chunk rA = load_s_chunk(c1b, 0, t);
    write_chunk(stg0, rA, t);
    Chunk rB = load_s_chunk(c1b, 1, t);
    __syncthreads();

    #pragma unroll
    for (int mc = 0; mc < 14; ++mc) {
        unsigned char* bufc = (mc & 1) ? stg1 : stg0;
        unsigned char* bufn = (mc & 1) ? stg0 : stg1;
        if (mc + 1 < 14) write_chunk(bufn, (mc & 1) ? rA : rB, t);
        if (mc + 2 < 14) {
            if (mc & 1) rB = load_s_chunk(c1b, mc + 2, t);
            else        rA = load_s_chunk(c1b, mc + 2, t);
        }
        // compute: B-frags from staged chunk, 8 MFMA, write S swizzled
        {
            int mloc = wq * 16 + l15;
            bf16x8 bfr[4];
            #pragma unroll
            for (int k = 0; k < 4; ++k)
                bfr[k] = *(const bf16x8*)(bufc + mloc * 256 + (((k * 4 + lg) ^ l15) * 16));
            f32x4 a0 = {0.f, 0.f, 0.f, 0.f}, a1 = {0.f, 0.f, 0.f, 0.f};
            #pragma unroll
            for (int k = 0; k < 4; ++k) {
                a0 = __builtin_amdgcn_mfma_f32_16x16x32_bf16(afr[0][k], bfr[k], a0, 0, 0, 0);
                a1 = __builtin_amdgcn_mfma_f32_16x16x32_bf16(afr[1][k], bfr[k], a1, 0, 0, 0);
            }
            int m = mc * 64 + mloc;
            #pragma unroll
            for (int r = 0; r < 4; ++r) {
                int na = wn * 32 + lg * 4 + r;
                *(bf16*)(smem + ((na * 1792 + m * 2) ^ ((na & 7) << 4))) = (bf16)a0[r];
                int nbr = na + 16;
                *(bf16*)(smem + ((nbr * 1792 + m * 2) ^ ((nbr & 7) << 4))) = (bf16)a1[r];
            }
        }
        __syncthreads();
    }

    // issue PV chunk-0 global loads now; softmax hides their latency
    rA = load_pv_chunk(c3b, 0, t);

    // ---------------- softmax over m (8 rows per wave) ----------------------
    #pragma unroll
    for (int rr = 0; rr < 8; ++rr) {
        int n = wave * 8 + rr;
        int rowbase = n * 1792, sw = (n & 7) << 4;
        float v[13];
        float mx = -1e30f;
        #pragma unroll
        for (int i = 0; i < 13; ++i) {
            int m = lane + 64 * i;
            v[i] = (m < MPOOL) ? (float)*(const bf16*)(smem + ((rowbase + 2 * m) ^ sw))
                               : -1e30f;
            mx = fmaxf(mx, v[i]);
        }
        #pragma unroll
        for (int off = 32; off; off >>= 1) mx = fmaxf(mx, __shfl_xor(mx, off));
        float s = 0.f;
        float e[13];
        #pragma unroll
        for (int i = 0; i < 13; ++i) {
            int m = lane + 64 * i;
            e[i] = (m < MPOOL) ? __expf(v[i] - mx) : 0.f;
            s += e[i];
        }
        #pragma unroll
        for (int off = 32; off; off >>= 1) s += __shfl_xor(s, off);
        float ri = 1.f / s;
        #pragma unroll
        for (int i = 0; i < 14; ++i) {
            int m = lane + 64 * i;
            float pv = (i < 13) ? e[i] * ri : 0.f;
            *(bf16*)(smem + ((rowbase + 2 * m) ^ sw)) = (bf16)pv;
        }
    }
    __syncthreads();

    // ---------------- Phase PV: pipelined over 28 chunks of 32 m ------------
    write_chunk(stg0, rA, t);
    rB = load_pv_chunk(c3b, 1, t);
    __syncthreads();

    f32x4 acc2[2][4];
    #pragma unroll
    for (int fn = 0; fn < 2; ++fn)
        #pragma unroll
        for (int fc = 0; fc < 4; ++fc) {
            f32x4 z = {0.f, 0.f, 0.f, 0.f};
            acc2[fn][fc] = z;
        }

    #pragma unroll
    for (int ks = 0; ks < 28; ++ks) {
        unsigned char* bufc = (ks & 1) ? stg1 : stg0;
        unsigned char* bufn = (ks & 1) ? stg0 : stg1;
        if (ks + 1 < 28) write_chunk(bufn, (ks & 1) ? rA : rB, t);
        if (ks + 2 < 28) {
            if (ks & 1) rB = load_pv_chunk(c3b, ks + 2, t);
            else        rA = load_pv_chunk(c3b, ks + 2, t);
        }
        {
            int nA0 = wn * 32 + l15, nA1 = nA0 + 16;
            int mb = (ks * 32 + lg * 8) * 2;
            bf16x8 af0 = *(const bf16x8*)(smem + ((nA0 * 1792 + mb) ^ ((nA0 & 7) << 4)));
            bf16x8 af1 = *(const bf16x8*)(smem + ((nA1 * 1792 + mb) ^ ((nA1 & 7) << 4)));
            #pragma unroll
            for (int fc = 0; fc < 4; ++fc) {
                int c = wq * 64 + fc * 16 + l15;
                bf16x8 bfr = *(const bf16x8*)(bufc + c * 64 + ((lg ^ (c & 3)) * 16));
                acc2[0][fc] = __builtin_amdgcn_mfma_f32_16x16x32_bf16(af0, bfr, acc2[0][fc], 0, 0, 0);
                acc2[1][fc] = __builtin_amdgcn_mfma_f32_16x16x32_bf16(af1, bfr, acc2[1][fc], 0, 0, 0);
            }
        }
        __syncthreads();
    }

    // ---------------- epilogue: transpose via LDS, out = g*refined + x ------
    float* R = (float*)smem;
    #pragma unroll
    for (int fn = 0; fn < 2; ++fn)
        #pragma unroll
        for (int fc = 0; fc < 4; ++fc) {
            int c = wq * 64 + fc * 16 + l15;
            #pragma unroll
            for (int r = 0; r < 4; ++r) {
                int n = wn * 32 + fn * 16 + lg * 4 + r;
                R[n * 257 + c] = acc2[fn][fc][r];
            }
        }
    __syncthreads();
    const float g = gamma[0];
    const float* xb = x + (size_t)b * CIN * NPIX + n0;
    float* ob = out + (size_t)b * CIN * NPIX + n0;
    #pragma unroll 4
    for (int i = 0; i < 32; ++i) {
        int idx = t + i * 512;                  // 256 c x 64 n
        int c = idx >> 6, nn = idx & 63;
        size_t off = (size_t)c * NPIX + nn;
        ob[off] = g * R[nn * 257 + c] + xb[off];
    }
}

extern "C" void kernel_launch(void* const* d_in, const int* in_sizes, int n_in,
                              void* d_out, int out_size, void* d_ws, size_t ws_size,
                              hipStream_t stream) {
    const float* x     = (const float*)d_in[0];
    const float* W1    = (const float*)d_in[1];
    const float* W2    = (const float*)d_in[2];
    const float* W3    = (const float*)d_in[3];
    const float* gamma = (const float*)d_in[4];
    float* out = (float*)d_out;

    bf16* ws   = (bf16*)d_ws;
    bf16* Wcat = ws;                                       // 512*256
    bf16* c2n  = Wcat + (size_t)512 * 256;                 // 32*3136*128
    bf16* c1pT = c2n + (size_t)BATCH * NPIX * CHALF;       // 32*896*128
    bf16* c3p  = c1pT + (size_t)BATCH * MPAD * CHALF;      // 32*256*896

    k_cast<<<128, 256, 0, stream>>>(W1, W2, W3, Wcat);
    k_conv<<<dim3(28, BATCH), 512, 0, stream>>>(x, Wcat, c2n, c1pT, c3p);
    k_attn<<<dim3(49, BATCH), 512, 0, stream>>>(c2n, c1pT, c3p, x, gamma, out);
}